// Round 1
// baseline (379.689 us; speedup 1.0000x reference)
//
#include <hip/hip_runtime.h>

// Fused BN(affine)+ReLU -> 2x2 AvgPool -> 1x1 Conv (channel GEMM 32->16).
// x: [32, 32, 256, 256] fp32, w: [32, 16] fp32, scale/bias: [32] fp32
// out: [32, 16, 128, 128] fp32
//
// Memory-bound: 268 MB in + 33.5 MB out => ~48 us floor at 6.3 TB/s.
// One thread = 2 adjacent output pixels (w pair): reads 2 rows x float4
// per input channel (16 B/lane coalesced), accumulates 16 C_out x 2 px.

#define C_IN  32
#define C_OUT 16
#define H_IN  256
#define W_IN  256
#define H_OUT 128
#define W_OUT 128

__global__ __launch_bounds__(256) void fused_bn_relu_pool_conv(
    const float* __restrict__ x,
    const float* __restrict__ w,      // [C_IN][C_OUT]
    const float* __restrict__ scale,  // [C_IN]
    const float* __restrict__ bias,   // [C_IN]
    float* __restrict__ out)
{
    __shared__ float s_w[C_IN * C_OUT];
    __shared__ float s_scale[C_IN];
    __shared__ float s_bias[C_IN];

    const int tid = threadIdx.x;
    for (int i = tid; i < C_IN * C_OUT; i += 256) s_w[i] = w[i];
    if (tid < C_IN) { s_scale[tid] = scale[tid]; s_bias[tid] = bias[tid]; }
    __syncthreads();

    // Global pixel-pair index: wp in [0,64), h in [0,128), n in [0,32)
    const int gid = blockIdx.x * 256 + tid;
    const int wp = gid & 63;
    const int h  = (gid >> 6) & 127;
    const int n  = gid >> 13;

    const float* xbase = x + ((size_t)(n * C_IN) * H_IN + 2 * h) * W_IN + 4 * wp;

    float acc0[C_OUT], acc1[C_OUT];
    #pragma unroll
    for (int d = 0; d < C_OUT; ++d) { acc0[d] = 0.f; acc1[d] = 0.f; }

    #pragma unroll 4
    for (int c = 0; c < C_IN; ++c) {
        const float* p = xbase + (size_t)c * (H_IN * W_IN);
        const float4 r0 = *reinterpret_cast<const float4*>(p);
        const float4 r1 = *reinterpret_cast<const float4*>(p + W_IN);
        const float s = s_scale[c];
        const float b = s_bias[c];

        const float v0 = fmaxf(fmaf(r0.x, s, b), 0.f);
        const float v1 = fmaxf(fmaf(r0.y, s, b), 0.f);
        const float v2 = fmaxf(fmaf(r0.z, s, b), 0.f);
        const float v3 = fmaxf(fmaf(r0.w, s, b), 0.f);
        const float u0 = fmaxf(fmaf(r1.x, s, b), 0.f);
        const float u1 = fmaxf(fmaf(r1.y, s, b), 0.f);
        const float u2 = fmaxf(fmaf(r1.z, s, b), 0.f);
        const float u3 = fmaxf(fmaf(r1.w, s, b), 0.f);

        const float p0 = (v0 + v1 + u0 + u1) * 0.25f;
        const float p1 = (v2 + v3 + u2 + u3) * 0.25f;

        #pragma unroll
        for (int d = 0; d < C_OUT; ++d) {
            const float wd = s_w[c * C_OUT + d];
            acc0[d] = fmaf(p0, wd, acc0[d]);
            acc1[d] = fmaf(p1, wd, acc1[d]);
        }
    }

    float* obase = out + ((size_t)(n * C_OUT) * H_OUT + h) * W_OUT + 2 * wp;
    #pragma unroll
    for (int d = 0; d < C_OUT; ++d) {
        float2 v = make_float2(acc0[d], acc1[d]);
        *reinterpret_cast<float2*>(obase + (size_t)d * (H_OUT * W_OUT)) = v;
    }
}

extern "C" void kernel_launch(void* const* d_in, const int* in_sizes, int n_in,
                              void* d_out, int out_size, void* d_ws, size_t ws_size,
                              hipStream_t stream) {
    const float* x     = (const float*)d_in[0];
    const float* w     = (const float*)d_in[1];
    const float* scale = (const float*)d_in[2];
    const float* bias  = (const float*)d_in[3];
    float* out = (float*)d_out;

    // 32 n * 128 h * 64 w-pairs = 262144 threads = 1024 blocks of 256
    const int total = 32 * H_OUT * (W_OUT / 2);
    fused_bn_relu_pool_conv<<<total / 256, 256, 0, stream>>>(x, w, scale, bias, out);
}

// Round 3
// 355.342 us; speedup vs baseline: 1.0685x; 1.0685x over previous
//
#include <hip/hip_runtime.h>

// Fused BN(affine)+ReLU -> 2x2 AvgPool -> 1x1 Conv (channel GEMM 32->16).
// x: [32, 32, 256, 256] fp32, w: [32, 16] fp32, scale/bias: [32] fp32
// out: [32, 16, 128, 128] fp32
//
// Memory-bound: 268 MB in + 33.5 MB out => ~48 us floor at 6.3 TB/s.
// One thread = 2 adjacent output pixels (w pair): reads 2 rows x float4
// per input channel (16 B/lane coalesced), accumulates 16 C_out x 2 px.
// R1: unroll 8, ds_read_b128 weight reads, 0.25 folded into weights,
// nontemporal loads/stores (stream-once data, skip L2 retention).
// R2: use clang ext_vector_type for nontemporal builtins (HIP_vector_type
// structs are rejected by __builtin_nontemporal_*).

#define C_IN  32
#define C_OUT 16
#define H_IN  256
#define W_IN  256
#define H_OUT 128
#define W_OUT 128

typedef float f32x4 __attribute__((ext_vector_type(4)));
typedef float f32x2 __attribute__((ext_vector_type(2)));

__global__ __launch_bounds__(256) void fused_bn_relu_pool_conv(
    const float* __restrict__ x,
    const float* __restrict__ w,      // [C_IN][C_OUT]
    const float* __restrict__ scale,  // [C_IN]
    const float* __restrict__ bias,   // [C_IN]
    float* __restrict__ out)
{
    __shared__ float s_w[C_IN * C_OUT];   // pre-scaled by 0.25 (pool mean)
    __shared__ float s_scale[C_IN];
    __shared__ float s_bias[C_IN];

    const int tid = threadIdx.x;
    for (int i = tid; i < C_IN * C_OUT; i += 256) s_w[i] = w[i] * 0.25f;
    if (tid < C_IN) { s_scale[tid] = scale[tid]; s_bias[tid] = bias[tid]; }
    __syncthreads();

    // Global pixel-pair index: wp in [0,64), h in [0,128), n in [0,32)
    const int gid = blockIdx.x * 256 + tid;
    const int wp = gid & 63;
    const int h  = (gid >> 6) & 127;
    const int n  = gid >> 13;

    const float* xbase = x + ((size_t)(n * C_IN) * H_IN + 2 * h) * W_IN + 4 * wp;

    float acc0[C_OUT], acc1[C_OUT];
    #pragma unroll
    for (int d = 0; d < C_OUT; ++d) { acc0[d] = 0.f; acc1[d] = 0.f; }

    #pragma unroll 8
    for (int c = 0; c < C_IN; ++c) {
        const float* p = xbase + c * (H_IN * W_IN);
        const f32x4 r0 = __builtin_nontemporal_load(reinterpret_cast<const f32x4*>(p));
        const f32x4 r1 = __builtin_nontemporal_load(reinterpret_cast<const f32x4*>(p + W_IN));
        const float s = s_scale[c];
        const float b = s_bias[c];

        const float v0 = fmaxf(fmaf(r0.x, s, b), 0.f);
        const float v1 = fmaxf(fmaf(r0.y, s, b), 0.f);
        const float v2 = fmaxf(fmaf(r0.z, s, b), 0.f);
        const float v3 = fmaxf(fmaf(r0.w, s, b), 0.f);
        const float u0 = fmaxf(fmaf(r1.x, s, b), 0.f);
        const float u1 = fmaxf(fmaf(r1.y, s, b), 0.f);
        const float u2 = fmaxf(fmaf(r1.z, s, b), 0.f);
        const float u3 = fmaxf(fmaf(r1.w, s, b), 0.f);

        // 0.25 is folded into s_w
        const float p0 = (v0 + v1) + (u0 + u1);
        const float p1 = (v2 + v3) + (u2 + u3);

        // Vectorized weight reads: 4x ds_read_b128 instead of 16x ds_read_b32
        const float4 w0 = *reinterpret_cast<const float4*>(&s_w[c * C_OUT + 0]);
        const float4 w1 = *reinterpret_cast<const float4*>(&s_w[c * C_OUT + 4]);
        const float4 w2 = *reinterpret_cast<const float4*>(&s_w[c * C_OUT + 8]);
        const float4 w3 = *reinterpret_cast<const float4*>(&s_w[c * C_OUT + 12]);

        acc0[ 0] = fmaf(p0, w0.x, acc0[ 0]); acc1[ 0] = fmaf(p1, w0.x, acc1[ 0]);
        acc0[ 1] = fmaf(p0, w0.y, acc0[ 1]); acc1[ 1] = fmaf(p1, w0.y, acc1[ 1]);
        acc0[ 2] = fmaf(p0, w0.z, acc0[ 2]); acc1[ 2] = fmaf(p1, w0.z, acc1[ 2]);
        acc0[ 3] = fmaf(p0, w0.w, acc0[ 3]); acc1[ 3] = fmaf(p1, w0.w, acc1[ 3]);
        acc0[ 4] = fmaf(p0, w1.x, acc0[ 4]); acc1[ 4] = fmaf(p1, w1.x, acc1[ 4]);
        acc0[ 5] = fmaf(p0, w1.y, acc0[ 5]); acc1[ 5] = fmaf(p1, w1.y, acc1[ 5]);
        acc0[ 6] = fmaf(p0, w1.z, acc0[ 6]); acc1[ 6] = fmaf(p1, w1.z, acc1[ 6]);
        acc0[ 7] = fmaf(p0, w1.w, acc0[ 7]); acc1[ 7] = fmaf(p1, w1.w, acc1[ 7]);
        acc0[ 8] = fmaf(p0, w2.x, acc0[ 8]); acc1[ 8] = fmaf(p1, w2.x, acc1[ 8]);
        acc0[ 9] = fmaf(p0, w2.y, acc0[ 9]); acc1[ 9] = fmaf(p1, w2.y, acc1[ 9]);
        acc0[10] = fmaf(p0, w2.z, acc0[10]); acc1[10] = fmaf(p1, w2.z, acc1[10]);
        acc0[11] = fmaf(p0, w2.w, acc0[11]); acc1[11] = fmaf(p1, w2.w, acc1[11]);
        acc0[12] = fmaf(p0, w3.x, acc0[12]); acc1[12] = fmaf(p1, w3.x, acc1[12]);
        acc0[13] = fmaf(p0, w3.y, acc0[13]); acc1[13] = fmaf(p1, w3.y, acc1[13]);
        acc0[14] = fmaf(p0, w3.z, acc0[14]); acc1[14] = fmaf(p1, w3.z, acc1[14]);
        acc0[15] = fmaf(p0, w3.w, acc0[15]); acc1[15] = fmaf(p1, w3.w, acc1[15]);
    }

    float* obase = out + ((size_t)(n * C_OUT) * H_OUT + h) * W_OUT + 2 * wp;
    #pragma unroll
    for (int d = 0; d < C_OUT; ++d) {
        f32x2 v; v.x = acc0[d]; v.y = acc1[d];
        __builtin_nontemporal_store(v, reinterpret_cast<f32x2*>(obase + (size_t)d * (H_OUT * W_OUT)));
    }
}

extern "C" void kernel_launch(void* const* d_in, const int* in_sizes, int n_in,
                              void* d_out, int out_size, void* d_ws, size_t ws_size,
                              hipStream_t stream) {
    const float* x     = (const float*)d_in[0];
    const float* w     = (const float*)d_in[1];
    const float* scale = (const float*)d_in[2];
    const float* bias  = (const float*)d_in[3];
    float* out = (float*)d_out;

    // 32 n * 128 h * 64 w-pairs = 262144 threads = 1024 blocks of 256
    const int total = 32 * H_OUT * (W_OUT / 2);
    fused_bn_relu_pool_conv<<<total / 256, 256, 0, stream>>>(x, w, scale, bias, out);
}

// Round 4
// 351.209 us; speedup vs baseline: 1.0811x; 1.0118x over previous
//
#include <hip/hip_runtime.h>

// Fused BN(affine)+ReLU -> 2x2 AvgPool -> 1x1 Conv (channel GEMM 32->16).
// x: [32, 32, 256, 256] fp32, w: [32, 16] fp32, scale/bias: [32] fp32
// out: [32, 16, 128, 128] fp32
//
// Memory-bound: 268 MB in + 33.5 MB out => ~48 us floor at 6.3 TB/s.
// One thread = 2 adjacent output pixels (w pair): reads 2 rows x float4
// per input channel (16 B/lane coalesced), accumulates 16 C_out x 2 px.
// R1: unroll 8, nontemporal loads/stores (stream-once data).
// R3: NO LDS — weights/scale/bias are wave-uniform, loaded via scalar
// (s_load) path directly from global; packed f32 math (v_pk_fma_f32 /
// v_pk_max_f32): GEMM inner step is 16 pk_fma on {pix0,pix1} pairs
// instead of 32 scalar fmac. Pool 0.25 applied as one pk_mul per channel.

#define C_IN  32
#define C_OUT 16
#define H_IN  256
#define W_IN  256
#define H_OUT 128
#define W_OUT 128

typedef float f32x4 __attribute__((ext_vector_type(4)));
typedef float f32x2 __attribute__((ext_vector_type(2)));

__global__ __launch_bounds__(256) void fused_bn_relu_pool_conv(
    const float* __restrict__ x,
    const float* __restrict__ w,      // [C_IN][C_OUT]
    const float* __restrict__ scale,  // [C_IN]
    const float* __restrict__ bias,   // [C_IN]
    float* __restrict__ out)
{
    // Global pixel-pair index: wp in [0,64), h in [0,128), n in [0,32)
    const int gid = blockIdx.x * 256 + threadIdx.x;
    const int wp = gid & 63;
    const int h  = (gid >> 6) & 127;
    const int n  = gid >> 13;

    const float* xbase = x + ((size_t)(n * C_IN) * H_IN + 2 * h) * W_IN + 4 * wp;

    f32x2 acc[C_OUT];
    #pragma unroll
    for (int d = 0; d < C_OUT; ++d) acc[d] = (f32x2)0.f;

    #pragma unroll 8
    for (int c = 0; c < C_IN; ++c) {
        const float* p = xbase + c * (H_IN * W_IN);
        const f32x4 r0 = __builtin_nontemporal_load(reinterpret_cast<const f32x4*>(p));
        const f32x4 r1 = __builtin_nontemporal_load(reinterpret_cast<const f32x4*>(p + W_IN));

        // Uniform addresses -> scalar loads into SGPRs (no LDS, no VGPR cost)
        const float s = scale[c];
        const float b = bias[c];

        // BN + ReLU, packed (v_pk_fma_f32 + v_pk_max_f32)
        f32x4 t0 = r0 * s + b;
        f32x4 t1 = r1 * s + b;
        t0 = __builtin_elementwise_max(t0, (f32x4)0.f);
        t1 = __builtin_elementwise_max(t1, (f32x4)0.f);

        // 2x2 pool: vertical pk_add, horizontal scalar adds, 0.25 as pk_mul
        const f32x4 t = t0 + t1;
        f32x2 pp;
        pp.x = t.x + t.y;
        pp.y = t.z + t.w;
        pp *= 0.25f;

        // Channel GEMM: 16 v_pk_fma_f32, weight operand from SGPR (s_load)
        #pragma unroll
        for (int d = 0; d < C_OUT; ++d) {
            acc[d] += pp * w[c * C_OUT + d];
        }
    }

    float* obase = out + ((size_t)(n * C_OUT) * H_OUT + h) * W_OUT + 2 * wp;
    #pragma unroll
    for (int d = 0; d < C_OUT; ++d) {
        __builtin_nontemporal_store(acc[d], reinterpret_cast<f32x2*>(obase + (size_t)d * (H_OUT * W_OUT)));
    }
}

extern "C" void kernel_launch(void* const* d_in, const int* in_sizes, int n_in,
                              void* d_out, int out_size, void* d_ws, size_t ws_size,
                              hipStream_t stream) {
    const float* x     = (const float*)d_in[0];
    const float* w     = (const float*)d_in[1];
    const float* scale = (const float*)d_in[2];
    const float* bias  = (const float*)d_in[3];
    float* out = (float*)d_out;

    // 32 n * 128 h * 64 w-pairs = 262144 threads = 1024 blocks of 256
    const int total = 32 * H_OUT * (W_OUT / 2);
    fused_bn_relu_pool_conv<<<total / 256, 256, 0, stream>>>(x, w, scale, bias, out);
}